// Round 1
// baseline (517.892 us; speedup 1.0000x reference)
//
#include <hip/hip_runtime.h>

typedef __bf16 bf16_t;
typedef __bf16 bf16x8 __attribute__((ext_vector_type(8)));
typedef float f32x4 __attribute__((ext_vector_type(4)));

#define LOG2E 1.4426950408889634f

template<int CTRL>
__device__ __forceinline__ float qperm(float x) {
  return __builtin_bit_cast(float,
      __builtin_amdgcn_update_dpp(0, __builtin_bit_cast(int, x), CTRL, 0xF, 0xF, true));
}

// ---------------------------------------------------------------------------
// K1: pre[dir][step][r] = (Wih_dir @ x[t_x]) + bih + bhh, gate-interleaved:
//     r = 4n + p  <->  original row j = 125*p + n   (n<125 valid, else 0)
//     t_x = step (fwd) or 511-step (bwd)
// ---------------------------------------------------------------------------
__global__ __launch_bounds__(256) void pre_kernel(
    const float* __restrict__ x,     // [512][125]
    const float* __restrict__ Wih_f, const float* __restrict__ bih_f,
    const float* __restrict__ bhh_f,
    const float* __restrict__ Wih_b, const float* __restrict__ bih_b,
    const float* __restrict__ bhh_b,
    float* __restrict__ pre)         // [2][512][512]
{
  const int bid = blockIdx.x;        // 256 blocks
  const int dir = bid >> 7;
  const int sc  = bid & 127;
  const int s0  = sc * 4;
  const float* __restrict__ Wih = dir ? Wih_b : Wih_f;
  const float* __restrict__ bih = dir ? bih_b : bih_f;
  const float* __restrict__ bhh = dir ? bhh_b : bhh_f;
  const int tid = threadIdx.x;

  int   jrow[2];
  bool  val[2];
  float acc[2][4];
  #pragma unroll
  for (int u = 0; u < 2; ++u) {
    int r = tid + 256 * u;
    int n = r >> 2, pp = r & 3;
    val[u]  = (n < 125);
    jrow[u] = 125 * pp + n;
    float bias = val[u] ? (bih[jrow[u]] + bhh[jrow[u]]) : 0.0f;
    #pragma unroll
    for (int si = 0; si < 4; ++si) acc[u][si] = bias;
  }
  int tx[4];
  #pragma unroll
  for (int si = 0; si < 4; ++si)
    tx[si] = dir ? (511 - (s0 + si)) : (s0 + si);

  for (int d = 0; d < 125; ++d) {
    float w0 = val[0] ? Wih[jrow[0] * 125 + d] : 0.0f;
    float w1 = val[1] ? Wih[jrow[1] * 125 + d] : 0.0f;
    #pragma unroll
    for (int si = 0; si < 4; ++si) {
      float xv = x[tx[si] * 125 + d];       // uniform -> scalarized
      acc[0][si] = fmaf(w0, xv, acc[0][si]);
      acc[1][si] = fmaf(w1, xv, acc[1][si]);
    }
  }
  #pragma unroll
  for (int si = 0; si < 4; ++si) {
    pre[dir * 262144 + (s0 + si) * 512 + tid]       = acc[0][si];
    pre[dir * 262144 + (s0 + si) * 512 + tid + 256] = acc[1][si];
  }
}

// ---------------------------------------------------------------------------
// K2: sequential LSTM.  grid = 2 blocks (dir), 512 threads (8 waves).
// Whh@h via mfma_f32_16x16x32_bf16. A = gate-interleaved Whh (in VGPR frags),
// B = h replicated across 16 cols (LDS-staged, double buffered).
// Lane 16q + 4lt + p owns gate p of unit n = 16w + 4lt + q.
// ---------------------------------------------------------------------------
__global__ __launch_bounds__(512) void lstm_kernel(
    const float* __restrict__ Whh_f, const float* __restrict__ Whh_b,
    const float* __restrict__ pre,   // [2][512][512]
    bf16_t* __restrict__ h_all)      // [512][256]  (0:125 fwd | 125:250 bwd | 250:256 zero pad)
{
  const int dir = blockIdx.x;
  const float* __restrict__ Whh  = dir ? Whh_b : Whh_f;
  const float* __restrict__ preD = pre + dir * 262144;

  const int tid  = threadIdx.x;
  const int lane = tid & 63;
  const int w    = tid >> 6;      // wave 0..7
  const int q    = lane >> 4;     // 0..3
  const int cc   = lane & 15;
  const int lt   = cc >> 2;       // local tile 0..3
  const int p    = cc & 3;        // gate index

  // ---- A fragments: afrag[lt][ks], A[m=cc][k=32ks+8q+j] of tile T=4w+lt ----
  bf16x8 afrag[4][4];
  #pragma unroll
  for (int LT = 0; LT < 4; ++LT) {
    int T  = 4 * w + LT;
    int r  = 16 * T + cc;              // reordered row
    int na = r >> 2, pa = r & 3;
    bool vld = (na < 125);
    int ja = 125 * pa + na;            // original Whh row
    #pragma unroll
    for (int ks = 0; ks < 4; ++ks) {
      bf16x8 v;
      #pragma unroll
      for (int jj = 0; jj < 8; ++jj) {
        int k = 32 * ks + 8 * q + jj;
        float xv = (vld && k < 125) ? Whh[ja * 125 + k] : 0.0f;
        v[jj] = (bf16_t)xv;
      }
      afrag[LT][ks] = v;
    }
  }

  __shared__ __align__(16) bf16_t hbuf[2][128];
  if (tid < 128) { hbuf[0][tid] = (bf16_t)0.0f; hbuf[1][tid] = (bf16_t)0.0f; }
  __syncthreads();

  const int   r_lane = 64 * w + 16 * lt + 4 * q + p;
  const int   nset   = 16 * w + 4 * lt + q;
  const float mult = (p == 2) ? (-2.0f * LOG2E) : (-LOG2E);
  const float sA   = (p == 2) ? 2.0f : 1.0f;
  const float sB   = (p == 2) ? -1.0f : 0.0f;
  float c = 0.0f;

  for (int step = 0; step < 512; ++step) {
    const int cur = step & 1, nxt = cur ^ 1;
    float pv = preD[step * 512 + r_lane];          // overlaps with MFMAs

    bf16x8 bfr[4];
    #pragma unroll
    for (int ks = 0; ks < 4; ++ks)
      bfr[ks] = *(const bf16x8*)&hbuf[cur][32 * ks + 8 * q];

    f32x4 acc[4];
    #pragma unroll
    for (int LT = 0; LT < 4; ++LT) acc[LT] = (f32x4)0.0f;
    #pragma unroll
    for (int ks = 0; ks < 4; ++ks) {
      #pragma unroll
      for (int LT = 0; LT < 4; ++LT)
        acc[LT] = __builtin_amdgcn_mfma_f32_16x16x32_bf16(
            afrag[LT][ks], bfr[ks], acc[LT], 0, 0, 0);
    }

    // select g for (lt, p) from own registers (divergent p/lt -> cndmasks)
    float gl[4];
    #pragma unroll
    for (int LT = 0; LT < 4; ++LT) {
      float a01 = (p & 1) ? acc[LT][1] : acc[LT][0];
      float a23 = (p & 1) ? acc[LT][3] : acc[LT][2];
      gl[LT] = (p & 2) ? a23 : a01;
    }
    float b01  = (lt & 1) ? gl[1] : gl[0];
    float b23  = (lt & 1) ? gl[3] : gl[2];
    float gsel = (lt & 2) ? b23 : b01;

    // uniform activation: y = sigmoid(scale*x); act = sA*y + sB
    float xg  = gsel + pv;
    float e   = __builtin_amdgcn_exp2f(mult * xg);
    float y   = __builtin_amdgcn_rcpf(1.0f + e);
    float act = fmaf(y, sA, sB);

    // quad: p0=i, p1=f, p2=g~, p3=o
    float t1   = qperm<0x4E>(act);      // perm(2,3,0,1): lane0 gets g~
    float prod = act * t1;              // lane0 = i*g~
    float big  = qperm<0x00>(prod);     // bcast lane0: i*g~
    float bf   = qperm<0x55>(act);      // bcast lane1: f
    c = fmaf(bf, c, big);               // c = f*c + i*g~   (replicated in quad)
    float e2 = __builtin_amdgcn_exp2f(-2.0f * LOG2E * c);
    float tc = fmaf(__builtin_amdgcn_rcpf(1.0f + e2), 2.0f, -1.0f);
    float bo = qperm<0xFF>(act);        // bcast lane3: o
    float h  = bo * tc;

    if (p == 0) {
      hbuf[nxt][nset] = (bf16_t)h;      // pad units (n>=125) stay exactly 0
      if (nset < 125) {
        int t_orig = dir ? (511 - step) : step;
        h_all[t_orig * 256 + dir * 125 + nset] = (bf16_t)h;
      }
    }
    if (dir == 0 && tid < 6)
      h_all[step * 256 + 250 + tid] = (bf16_t)0.0f;

    __syncthreads();
  }
}

// ---------------------------------------------------------------------------
// K3: Qa[j][m] = C2 * (h @ W1[:, :250].T),  Qb[j][m] = C2 * (h @ W1[:, 250:].T + b1)
//     C2 = 2*log2(e) folded in for K4's exp2.  bf16 MFMA, one 16x16 tile/wave.
// ---------------------------------------------------------------------------
__global__ __launch_bounds__(256) void qgemm_kernel(
    const bf16_t* __restrict__ h_all, // [512][256]
    const float* __restrict__ W1,     // [512][500]
    const float* __restrict__ b1,     // [512]
    float* __restrict__ Qa,           // [512][512]
    float* __restrict__ Qb)           // [512][512]
{
  const int tid  = threadIdx.x;
  const int wv   = tid >> 6;
  const int lane = tid & 63;
  const int q    = lane >> 4, cc = lane & 15;
  const int bj   = blockIdx.x & 31;    // j tile
  const int bm   = blockIdx.x >> 5;    // m group
  const int m    = bm * 64 + wv * 16 + cc;   // [0,1024)
  const int j0   = bj * 16;
  const int jA   = j0 + cc;

  const bool isB = (m >= 512);
  const int  row = isB ? (m - 512) : m;
  const int  cof = isB ? 250 : 0;

  f32x4 acc = (f32x4)0.0f;
  #pragma unroll
  for (int ks = 0; ks < 8; ++ks) {
    int kb = 32 * ks + 8 * q;
    bf16x8 a = *(const bf16x8*)&h_all[jA * 256 + kb];
    bf16x8 b;
    #pragma unroll
    for (int jj = 0; jj < 8; ++jj) {
      int k = kb + jj;
      float v = (k < 250) ? W1[row * 500 + cof + k] : 0.0f;
      b[jj] = (bf16_t)v;
    }
    acc = __builtin_amdgcn_mfma_f32_16x16x32_bf16(a, b, acc, 0, 0, 0);
  }

  const float C2 = 2.0f * LOG2E;
  #pragma unroll
  for (int reg = 0; reg < 4; ++reg) {
    int j = j0 + 4 * q + reg;
    float v = acc[reg];
    if (!isB) Qa[j * 512 + m] = C2 * v;
    else      Qb[j * 512 + (m - 512)] = C2 * (v + b1[m - 512]);
  }
}

// ---------------------------------------------------------------------------
// K4: out[i][j] = b2 + sum_k W2[k] * tanh(...)
//     tanh = 1 - 2*rcp(1 + exp2(saQ[j,k] + sbQ[i,k]))   (C2 pre-folded)
//     accumulate accR = sum w*r;  out = wsum - 2*accR + b2
// ---------------------------------------------------------------------------
__global__ __launch_bounds__(256) void outer_kernel(
    const float* __restrict__ Qa, const float* __restrict__ Qb,
    const float* __restrict__ W2, const float* __restrict__ b2,
    float* __restrict__ out)
{
  __shared__ float sa[2][32][33];
  __shared__ float sb[2][32][33];
  __shared__ float sw[2][32];

  const int tid = threadIdx.x;
  const int bi  = blockIdx.x >> 4, bjx = blockIdx.x & 15;
  const int i0  = bi * 32, j0 = bjx * 32;
  const int ii0 = (tid & 15) * 2;
  const int jj0 = (tid >> 4) * 2;
  const int ljj = tid & 31, kk4 = (tid >> 5) * 4;

  float accR[2][2] = {{0.0f, 0.0f}, {0.0f, 0.0f}};
  float wsum = 0.0f;

  for (int kc = 0; kc < 16; ++kc) {
    const int buf = kc & 1;
    const int k0  = kc * 32;
    float4 va = *(const float4*)&Qa[(j0 + ljj) * 512 + k0 + kk4];
    float4 vb = *(const float4*)&Qb[(i0 + ljj) * 512 + k0 + kk4];
    sa[buf][kk4 + 0][ljj] = va.x; sa[buf][kk4 + 1][ljj] = va.y;
    sa[buf][kk4 + 2][ljj] = va.z; sa[buf][kk4 + 3][ljj] = va.w;
    sb[buf][kk4 + 0][ljj] = vb.x; sb[buf][kk4 + 1][ljj] = vb.y;
    sb[buf][kk4 + 2][ljj] = vb.z; sb[buf][kk4 + 3][ljj] = vb.w;
    if (tid < 32) sw[buf][tid] = W2[k0 + tid];
    __syncthreads();

    #pragma unroll 4
    for (int kk = 0; kk < 32; ++kk) {
      float2 av = *(const float2*)&sa[buf][kk][jj0];
      float2 bv = *(const float2*)&sb[buf][kk][ii0];
      float wk = sw[buf][kk];
      wsum += wk;
      {
        float e = __builtin_amdgcn_exp2f(av.x + bv.x);
        accR[0][0] = fmaf(wk, __builtin_amdgcn_rcpf(1.0f + e), accR[0][0]);
      }
      {
        float e = __builtin_amdgcn_exp2f(av.y + bv.x);
        accR[0][1] = fmaf(wk, __builtin_amdgcn_rcpf(1.0f + e), accR[0][1]);
      }
      {
        float e = __builtin_amdgcn_exp2f(av.x + bv.y);
        accR[1][0] = fmaf(wk, __builtin_amdgcn_rcpf(1.0f + e), accR[1][0]);
      }
      {
        float e = __builtin_amdgcn_exp2f(av.y + bv.y);
        accR[1][1] = fmaf(wk, __builtin_amdgcn_rcpf(1.0f + e), accR[1][1]);
      }
    }
  }

  const float bb = b2[0];
  #pragma unroll
  for (int i2 = 0; i2 < 2; ++i2)
    #pragma unroll
    for (int j2 = 0; j2 < 2; ++j2)
      out[(i0 + ii0 + i2) * 512 + (j0 + jj0 + j2)] =
          wsum - 2.0f * accR[i2][j2] + bb;
}

// ---------------------------------------------------------------------------
extern "C" void kernel_launch(void* const* d_in, const int* in_sizes, int n_in,
                              void* d_out, int out_size, void* d_ws, size_t ws_size,
                              hipStream_t stream) {
  const float* emb   = (const float*)d_in[0];
  const float* Wih_f = (const float*)d_in[1];
  const float* Whh_f = (const float*)d_in[2];
  const float* bih_f = (const float*)d_in[3];
  const float* bhh_f = (const float*)d_in[4];
  const float* Wih_b = (const float*)d_in[5];
  const float* Whh_b = (const float*)d_in[6];
  const float* bih_b = (const float*)d_in[7];
  const float* bhh_b = (const float*)d_in[8];
  const float* W1    = (const float*)d_in[9];
  const float* b1    = (const float*)d_in[10];
  const float* W2    = (const float*)d_in[11];
  const float* b2    = (const float*)d_in[12];
  float* out = (float*)d_out;

  char* ws = (char*)d_ws;
  float*  pre   = (float*)ws;                                  // 2 MB
  bf16_t* h_all = (bf16_t*)(ws + 2 * 1024 * 1024);             // 256 KB
  float*  Qa    = (float*)(ws + 2 * 1024 * 1024 + 256 * 1024); // 1 MB
  float*  Qb    = Qa + 512 * 512;                              // 1 MB

  pre_kernel<<<256, 256, 0, stream>>>(emb, Wih_f, bih_f, bhh_f,
                                      Wih_b, bih_b, bhh_b, pre);
  lstm_kernel<<<2, 512, 0, stream>>>(Whh_f, Whh_b, pre, h_all);
  qgemm_kernel<<<512, 256, 0, stream>>>(h_all, W1, b1, Qa, Qb);
  outer_kernel<<<256, 256, 0, stream>>>(Qa, Qb, W2, b2, out);
}

// Round 2
// 413.104 us; speedup vs baseline: 1.2537x; 1.2537x over previous
//
#include <hip/hip_runtime.h>

typedef __bf16 bf16_t;
typedef __bf16 bf16x8 __attribute__((ext_vector_type(8)));
typedef float f32x4 __attribute__((ext_vector_type(4)));

#define LOG2E 1.4426950408889634f

template<int CTRL>
__device__ __forceinline__ float qperm(float x) {
  return __builtin_bit_cast(float,
      __builtin_amdgcn_update_dpp(0, __builtin_bit_cast(int, x), CTRL, 0xF, 0xF, true));
}

// LDS-only barrier: does NOT drain vmcnt, so global loads/stores stay in
// flight across steps (compiler's __syncthreads drains vmcnt(0) every step).
__device__ __forceinline__ void lds_barrier() {
  asm volatile("s_waitcnt lgkmcnt(0)\n\ts_barrier" ::: "memory");
}

// ---------------------------------------------------------------------------
// K1: preT[dir][r][step] = (Wih_dir @ x[t_x]) + bih + bhh, gate-interleaved:
//     r = 4n + p  <->  original row j = 125*p + n   (n<125 valid, else 0)
//     t_x = step (fwd) or 511-step (bwd).  Layout transposed so the LSTM
//     kernel reads per-thread contiguous float4 rows.
// grid: 32 blocks (dir*16 + step-chunk), 512 threads; thread = one r, 32 steps
// ---------------------------------------------------------------------------
__global__ __launch_bounds__(512) void pre_kernel(
    const float* __restrict__ x,     // [512][125]
    const float* __restrict__ Wih_f, const float* __restrict__ bih_f,
    const float* __restrict__ bhh_f,
    const float* __restrict__ Wih_b, const float* __restrict__ bih_b,
    const float* __restrict__ bhh_b,
    float* __restrict__ preT)        // [2][512 r][512 step]
{
  const int dir = blockIdx.x >> 4;
  const int t0  = (blockIdx.x & 15) * 32;
  const int tid = threadIdx.x;
  const float* __restrict__ Wih = dir ? Wih_b : Wih_f;
  const float* __restrict__ bih = dir ? bih_b : bih_f;
  const float* __restrict__ bhh = dir ? bhh_b : bhh_f;

  __shared__ float xs[32][128];      // [s][d], row stride 128 for alignment

  // stage x rows for this chunk's 32 steps (coalesced)
  #pragma unroll
  for (int u = 0; u < 8; ++u) {
    int idx = tid + 512 * u;         // 0..4095, need 4000
    if (idx < 4000) {
      int s = idx / 125, d = idx - 125 * s;
      int grow = dir ? (511 - (t0 + s)) : (t0 + s);
      xs[s][d] = x[grow * 125 + d];
    }
  }
  __syncthreads();

  const int r = tid;
  const int n = r >> 2, p = r & 3;
  const bool valid = (n < 125);
  const int j = 125 * p + n;
  const float bias = valid ? (bih[j] + bhh[j]) : 0.0f;

  float acc[32];
  #pragma unroll
  for (int s = 0; s < 32; ++s) acc[s] = bias;

  #pragma unroll 1
  for (int d4 = 0; d4 < 31; ++d4) {
    float4 wv = make_float4(0.f, 0.f, 0.f, 0.f);
    if (valid) wv = *(const float4*)&Wih[j * 125 + 4 * d4];
    #pragma unroll
    for (int s = 0; s < 32; ++s) {
      float4 xv = *(const float4*)&xs[s][4 * d4];
      float a = acc[s];
      a = fmaf(wv.x, xv.x, a);
      a = fmaf(wv.y, xv.y, a);
      a = fmaf(wv.z, xv.z, a);
      a = fmaf(wv.w, xv.w, a);
      acc[s] = a;
    }
  }
  { // tail d = 124
    float wl = valid ? Wih[j * 125 + 124] : 0.0f;
    #pragma unroll
    for (int s = 0; s < 32; ++s) acc[s] = fmaf(wl, xs[s][124], acc[s]);
  }

  float* dst = preT + dir * 262144 + r * 512 + t0;
  #pragma unroll
  for (int s4 = 0; s4 < 8; ++s4)
    *(float4*)(dst + 4 * s4) =
        make_float4(acc[4 * s4], acc[4 * s4 + 1], acc[4 * s4 + 2], acc[4 * s4 + 3]);
}

// ---------------------------------------------------------------------------
// K2: sequential LSTM.  grid = 2 blocks (dir), 512 threads (8 waves).
// Whh@h via mfma_f32_16x16x32_bf16. A = gate-interleaved Whh (in VGPR frags),
// B = h replicated across 16 cols (LDS-staged, double buffered).
// Lane 16q + 4lt + p owns gate p of unit n = 16w + 4lt + q.
// preT read as per-thread contiguous float4 (one per 4 steps), prefetched one
// group ahead; LDS-only barrier keeps global traffic off the barrier drain.
// ---------------------------------------------------------------------------
__global__ __launch_bounds__(512) void lstm_kernel(
    const float* __restrict__ Whh_f, const float* __restrict__ Whh_b,
    const float* __restrict__ pre,   // [2][512 r][512 step]
    bf16_t* __restrict__ h_all)      // [512][256]  (0:125 fwd | 125:250 bwd | 250:256 zero)
{
  const int dir = blockIdx.x;
  const float* __restrict__ Whh = dir ? Whh_b : Whh_f;

  const int tid  = threadIdx.x;
  const int lane = tid & 63;
  const int w    = tid >> 6;      // wave 0..7
  const int q    = lane >> 4;     // 0..3
  const int cc   = lane & 15;
  const int lt   = cc >> 2;       // local tile 0..3
  const int p    = cc & 3;        // gate index

  // ---- A fragments: afrag[lt][ks], A[m=cc][k=32ks+8q+j] of tile T=4w+lt ----
  bf16x8 afrag[4][4];
  #pragma unroll
  for (int LT = 0; LT < 4; ++LT) {
    int T  = 4 * w + LT;
    int r  = 16 * T + cc;              // reordered row
    int na = r >> 2, pa = r & 3;
    bool vld = (na < 125);
    int ja = 125 * pa + na;            // original Whh row
    #pragma unroll
    for (int ks = 0; ks < 4; ++ks) {
      bf16x8 v;
      #pragma unroll
      for (int jj = 0; jj < 8; ++jj) {
        int k = 32 * ks + 8 * q + jj;
        float xv = (vld && k < 125) ? Whh[ja * 125 + k] : 0.0f;
        v[jj] = (bf16_t)xv;
      }
      afrag[LT][ks] = v;
    }
  }

  __shared__ __align__(16) bf16_t hbuf[2][128];
  if (tid < 128) { hbuf[0][tid] = (bf16_t)0.0f; hbuf[1][tid] = (bf16_t)0.0f; }
  // zero the h_all pad columns once (dir 0 only), outside the step loop
  if (dir == 0) {
    #pragma unroll
    for (int u = 0; u < 6; ++u) h_all[tid * 256 + 250 + u] = (bf16_t)0.0f;
  }
  __syncthreads();

  const int   r_lane = 64 * w + 16 * lt + 4 * q + p;
  const int   nset   = 16 * w + 4 * lt + q;
  const float mult = (p == 2) ? (-2.0f * LOG2E) : (-LOG2E);
  const float sA   = (p == 2) ? 2.0f : 1.0f;
  const float sB   = (p == 2) ? -1.0f : 0.0f;
  const float* __restrict__ preR = pre + dir * 262144 + r_lane * 512;
  float c = 0.0f;

  float4 pv_cur = *(const float4*)preR;

  for (int g = 0; g < 128; ++g) {
    float4 pv_nxt = make_float4(0.f, 0.f, 0.f, 0.f);
    if (g < 127) pv_nxt = *(const float4*)(preR + 4 * (g + 1));

    #pragma unroll
    for (int s4 = 0; s4 < 4; ++s4) {
      const int step = 4 * g + s4;
      const int cur  = s4 & 1, nxt = cur ^ 1;
      const float pv = (s4 == 0) ? pv_cur.x : (s4 == 1) ? pv_cur.y
                     : (s4 == 2) ? pv_cur.z : pv_cur.w;
      const float pvm = mult * pv;            // off critical path

      bf16x8 bfr[4];
      #pragma unroll
      for (int ks = 0; ks < 4; ++ks)
        bfr[ks] = *(const bf16x8*)&hbuf[cur][32 * ks + 8 * q];

      f32x4 acc[4];
      #pragma unroll
      for (int LT = 0; LT < 4; ++LT) acc[LT] = (f32x4)0.0f;
      #pragma unroll
      for (int ks = 0; ks < 4; ++ks) {
        #pragma unroll
        for (int LT = 0; LT < 4; ++LT)
          acc[LT] = __builtin_amdgcn_mfma_f32_16x16x32_bf16(
              afrag[LT][ks], bfr[ks], acc[LT], 0, 0, 0);
      }

      // select g for (lt, p) from own registers
      float gl[4];
      #pragma unroll
      for (int LT = 0; LT < 4; ++LT) {
        float a01 = (p & 1) ? acc[LT][1] : acc[LT][0];
        float a23 = (p & 1) ? acc[LT][3] : acc[LT][2];
        gl[LT] = (p & 2) ? a23 : a01;
      }
      float b01  = (lt & 1) ? gl[1] : gl[0];
      float b23  = (lt & 1) ? gl[3] : gl[2];
      float gsel = (lt & 2) ? b23 : b01;

      // uniform activation: y = sigmoid(scale*(gsel+pv)); act = sA*y + sB
      float xg  = fmaf(gsel, mult, pvm);
      float e   = __builtin_amdgcn_exp2f(xg);
      float y   = __builtin_amdgcn_rcpf(1.0f + e);
      float act = fmaf(y, sA, sB);

      // quad: p0=i, p1=f, p2=g~, p3=o
      float t1   = qperm<0x4E>(act);      // perm(2,3,0,1): lane0 gets g~
      float prod = act * t1;              // lane0 = i*g~
      float big  = qperm<0x00>(prod);     // bcast lane0: i*g~
      float bf   = qperm<0x55>(act);      // bcast lane1: f
      c = fmaf(bf, c, big);               // c = f*c + i*g~
      float e2 = __builtin_amdgcn_exp2f(-2.0f * LOG2E * c);
      float tc = fmaf(__builtin_amdgcn_rcpf(1.0f + e2), 2.0f, -1.0f);
      float bo = qperm<0xFF>(act);        // bcast lane3: o
      float h  = bo * tc;

      if (p == 0) {
        hbuf[nxt][nset] = (bf16_t)h;      // pad units (n>=125) write exact 0
        if (nset < 125) {
          int t_orig = dir ? (511 - step) : step;
          h_all[t_orig * 256 + dir * 125 + nset] = (bf16_t)h;
        }
      }
      lds_barrier();
    }
    pv_cur = pv_nxt;
  }
}

// ---------------------------------------------------------------------------
// K3: Qa[j][m] = C2 * (h @ W1[:, :250].T),  Qb[j][m] = C2 * (h @ W1[:, 250:].T + b1)
//     C2 = 2*log2(e) folded in for K4's exp2.  bf16 MFMA, one 16x16 tile/wave.
// ---------------------------------------------------------------------------
__global__ __launch_bounds__(256) void qgemm_kernel(
    const bf16_t* __restrict__ h_all, // [512][256]
    const float* __restrict__ W1,     // [512][500]
    const float* __restrict__ b1,     // [512]
    float* __restrict__ Qa,           // [512][512]
    float* __restrict__ Qb)           // [512][512]
{
  const int tid  = threadIdx.x;
  const int wv   = tid >> 6;
  const int lane = tid & 63;
  const int q    = lane >> 4, cc = lane & 15;
  const int bj   = blockIdx.x & 31;    // j tile
  const int bm   = blockIdx.x >> 5;    // m group
  const int m    = bm * 64 + wv * 16 + cc;   // [0,1024)
  const int j0   = bj * 16;
  const int jA   = j0 + cc;

  const bool isB = (m >= 512);
  const int  row = isB ? (m - 512) : m;
  const int  cof = isB ? 250 : 0;

  f32x4 acc = (f32x4)0.0f;
  #pragma unroll
  for (int ks = 0; ks < 8; ++ks) {
    int kb = 32 * ks + 8 * q;
    bf16x8 a = *(const bf16x8*)&h_all[jA * 256 + kb];
    bf16x8 b;
    #pragma unroll
    for (int jj = 0; jj < 8; ++jj) {
      int k = kb + jj;
      float v = (k < 250) ? W1[row * 500 + cof + k] : 0.0f;
      b[jj] = (bf16_t)v;
    }
    acc = __builtin_amdgcn_mfma_f32_16x16x32_bf16(a, b, acc, 0, 0, 0);
  }

  const float C2 = 2.0f * LOG2E;
  #pragma unroll
  for (int reg = 0; reg < 4; ++reg) {
    int j = j0 + 4 * q + reg;
    float v = acc[reg];
    if (!isB) Qa[j * 512 + m] = C2 * v;
    else      Qb[j * 512 + (m - 512)] = C2 * (v + b1[m - 512]);
  }
}

// ---------------------------------------------------------------------------
// K4: out[i][j] = b2 + sum_k W2[k] * tanh(...)
//     tanh = 1 - 2*rcp(1 + exp2(sa[j,k] + sb[i,k]))   (C2 pre-folded)
//     accumulate accR = sum w*r;  out = wsum - 2*accR + b2
// ---------------------------------------------------------------------------
__global__ __launch_bounds__(256) void outer_kernel(
    const float* __restrict__ Qa, const float* __restrict__ Qb,
    const float* __restrict__ W2, const float* __restrict__ b2,
    float* __restrict__ out)
{
  __shared__ float sa[2][32][33];
  __shared__ float sb[2][32][33];
  __shared__ float sw[2][32];

  const int tid = threadIdx.x;
  const int bi  = blockIdx.x >> 4, bjx = blockIdx.x & 15;
  const int i0  = bi * 32, j0 = bjx * 32;
  const int ii0 = (tid & 15) * 2;
  const int jj0 = (tid >> 4) * 2;
  const int ljj = tid & 31, kk4 = (tid >> 5) * 4;

  float accR[2][2] = {{0.0f, 0.0f}, {0.0f, 0.0f}};
  float wsum = 0.0f;

  for (int kc = 0; kc < 16; ++kc) {
    const int buf = kc & 1;
    const int k0  = kc * 32;
    float4 va = *(const float4*)&Qa[(j0 + ljj) * 512 + k0 + kk4];
    float4 vb = *(const float4*)&Qb[(i0 + ljj) * 512 + k0 + kk4];
    sa[buf][kk4 + 0][ljj] = va.x; sa[buf][kk4 + 1][ljj] = va.y;
    sa[buf][kk4 + 2][ljj] = va.z; sa[buf][kk4 + 3][ljj] = va.w;
    sb[buf][kk4 + 0][ljj] = vb.x; sb[buf][kk4 + 1][ljj] = vb.y;
    sb[buf][kk4 + 2][ljj] = vb.z; sb[buf][kk4 + 3][ljj] = vb.w;
    if (tid < 32) sw[buf][tid] = W2[k0 + tid];
    __syncthreads();

    #pragma unroll 4
    for (int kk = 0; kk < 32; ++kk) {
      float2 av = *(const float2*)&sa[buf][kk][jj0];
      float2 bv = *(const float2*)&sb[buf][kk][ii0];
      float wk = sw[buf][kk];
      wsum += wk;
      {
        float e = __builtin_amdgcn_exp2f(av.x + bv.x);
        accR[0][0] = fmaf(wk, __builtin_amdgcn_rcpf(1.0f + e), accR[0][0]);
      }
      {
        float e = __builtin_amdgcn_exp2f(av.y + bv.x);
        accR[0][1] = fmaf(wk, __builtin_amdgcn_rcpf(1.0f + e), accR[0][1]);
      }
      {
        float e = __builtin_amdgcn_exp2f(av.x + bv.y);
        accR[1][0] = fmaf(wk, __builtin_amdgcn_rcpf(1.0f + e), accR[1][0]);
      }
      {
        float e = __builtin_amdgcn_exp2f(av.y + bv.y);
        accR[1][1] = fmaf(wk, __builtin_amdgcn_rcpf(1.0f + e), accR[1][1]);
      }
    }
  }

  const float bb = b2[0];
  #pragma unroll
  for (int i2 = 0; i2 < 2; ++i2)
    #pragma unroll
    for (int j2 = 0; j2 < 2; ++j2)
      out[(i0 + ii0 + i2) * 512 + (j0 + jj0 + j2)] =
          wsum - 2.0f * accR[i2][j2] + bb;
}

// ---------------------------------------------------------------------------
extern "C" void kernel_launch(void* const* d_in, const int* in_sizes, int n_in,
                              void* d_out, int out_size, void* d_ws, size_t ws_size,
                              hipStream_t stream) {
  const float* emb   = (const float*)d_in[0];
  const float* Wih_f = (const float*)d_in[1];
  const float* Whh_f = (const float*)d_in[2];
  const float* bih_f = (const float*)d_in[3];
  const float* bhh_f = (const float*)d_in[4];
  const float* Wih_b = (const float*)d_in[5];
  const float* Whh_b = (const float*)d_in[6];
  const float* bih_b = (const float*)d_in[7];
  const float* bhh_b = (const float*)d_in[8];
  const float* W1    = (const float*)d_in[9];
  const float* b1    = (const float*)d_in[10];
  const float* W2    = (const float*)d_in[11];
  const float* b2    = (const float*)d_in[12];
  float* out = (float*)d_out;

  char* ws = (char*)d_ws;
  float*  pre   = (float*)ws;                                  // 2 MB
  bf16_t* h_all = (bf16_t*)(ws + 2 * 1024 * 1024);             // 256 KB
  float*  Qa    = (float*)(ws + 2 * 1024 * 1024 + 256 * 1024); // 1 MB
  float*  Qb    = Qa + 512 * 512;                              // 1 MB

  pre_kernel<<<32, 512, 0, stream>>>(emb, Wih_f, bih_f, bhh_f,
                                     Wih_b, bih_b, bhh_b, pre);
  lstm_kernel<<<2, 512, 0, stream>>>(Whh_f, Whh_b, pre, h_all);
  qgemm_kernel<<<512, 256, 0, stream>>>(h_all, W1, b1, Qa, Qb);
  outer_kernel<<<256, 256, 0, stream>>>(Qa, Qb, W2, b2, out);
}

// Round 3
// 336.398 us; speedup vs baseline: 1.5395x; 1.2280x over previous
//
#include <hip/hip_runtime.h>

typedef __bf16 bf16_t;
typedef __bf16 bf16x8 __attribute__((ext_vector_type(8)));
typedef float f32x4 __attribute__((ext_vector_type(4)));
typedef int   int4v __attribute__((ext_vector_type(4)));

#define LOG2E 1.4426950408889634f

template<int CTRL>
__device__ __forceinline__ float qperm(float x) {
  return __builtin_bit_cast(float,
      __builtin_amdgcn_update_dpp(0, __builtin_bit_cast(int, x), CTRL, 0xF, 0xF, true));
}

// LDS-only barrier: does NOT drain vmcnt, so global loads/stores stay in
// flight across steps (compiler's __syncthreads drains vmcnt(0) every step).
__device__ __forceinline__ void lds_barrier() {
  asm volatile("s_waitcnt lgkmcnt(0)\n\ts_barrier" ::: "memory");
}

// ---------------------------------------------------------------------------
// K1: preT[dir][r][t] = (Wih_dir @ x[t_x]) + bih + bhh, gate-interleaved rows:
//     r = 4n + p  <->  original row j = 125*p + n   (n<125 valid, else 0)
//     t_x = t (fwd) or 511-t (bwd).
// MFMA GEMM with bf16 hi/lo split (Whi*xhi + Whi*xlo + Wlo*xhi): fp32-exact
// to ~2^-18.  grid = 64 blocks (dir*32 + row-tile T), 256 threads (4 waves),
// each wave does 8 t-tiles of 16.
// ---------------------------------------------------------------------------
__global__ __launch_bounds__(256) void pre_kernel(
    const float* __restrict__ x,     // [512][125]
    const float* __restrict__ Wih_f, const float* __restrict__ bih_f,
    const float* __restrict__ bhh_f,
    const float* __restrict__ Wih_b, const float* __restrict__ bih_b,
    const float* __restrict__ bhh_b,
    float* __restrict__ preT)        // [2][512 r][512 t]
{
  const int dir = blockIdx.x >> 5;
  const int T   = blockIdx.x & 31;
  const float* __restrict__ Wih = dir ? Wih_b : Wih_f;
  const float* __restrict__ bih = dir ? bih_b : bih_f;
  const float* __restrict__ bhh = dir ? bhh_b : bhh_f;

  const int tid = threadIdx.x;
  const int wv  = tid >> 6;
  const int lane = tid & 63;
  const int q = lane >> 4, cc = lane & 15;

  // A fragments for row-tile T: row r = 16T + cc, k = 32ks + 8q + j
  const int r  = 16 * T + cc;
  const int na = r >> 2, pa = r & 3;
  const bool vld = (na < 125);
  const float* __restrict__ Wr = Wih + (vld ? (125 * pa + na) * 125 : 0);

  bf16x8 whi[4], wlo[4];
  #pragma unroll
  for (int ks = 0; ks < 4; ++ks) {
    #pragma unroll
    for (int j = 0; j < 8; ++j) {
      int k = 32 * ks + 8 * q + j;
      float wvv = (vld && k < 125) ? Wr[k] : 0.0f;
      bf16_t hi = (bf16_t)wvv;
      whi[ks][j] = hi;
      wlo[ks][j] = (bf16_t)(wvv - (float)hi);
    }
  }

  // bias for the 4 output rows this lane stores
  float bias[4];
  #pragma unroll
  for (int reg = 0; reg < 4; ++reg) {
    int ro = 16 * T + 4 * q + reg;
    int no = ro >> 2, po = ro & 3;
    bias[reg] = (no < 125) ? (bih[125 * po + no] + bhh[125 * po + no]) : 0.0f;
  }

  for (int i = 0; i < 8; ++i) {
    const int tt = 8 * wv + i;
    const int t  = 16 * tt + cc;
    const int trow = dir ? (511 - t) : t;
    const float* __restrict__ xr = x + trow * 125;

    f32x4 acc = (f32x4)0.0f;
    #pragma unroll
    for (int ks = 0; ks < 4; ++ks) {
      bf16x8 xhi, xlo;
      #pragma unroll
      for (int j = 0; j < 8; ++j) {
        int k = 32 * ks + 8 * q + j;
        float xv = (k < 125) ? xr[k] : 0.0f;
        bf16_t hi = (bf16_t)xv;
        xhi[j] = hi;
        xlo[j] = (bf16_t)(xv - (float)hi);
      }
      acc = __builtin_amdgcn_mfma_f32_16x16x32_bf16(whi[ks], xhi, acc, 0, 0, 0);
      acc = __builtin_amdgcn_mfma_f32_16x16x32_bf16(whi[ks], xlo, acc, 0, 0, 0);
      acc = __builtin_amdgcn_mfma_f32_16x16x32_bf16(wlo[ks], xhi, acc, 0, 0, 0);
    }
    #pragma unroll
    for (int reg = 0; reg < 4; ++reg) {
      int ro = 16 * T + 4 * q + reg;
      preT[dir * 262144 + ro * 512 + 16 * tt + cc] = acc[reg] + bias[reg];
    }
  }
}

// ---------------------------------------------------------------------------
// K2: sequential LSTM.  grid = 2 blocks (dir), 512 threads (8 waves).
// Whh@h via mfma_i32_16x16x64_i8 (int8 quantized: h scale 127 exact since
// |h|<1; W global scale 127/max|W| computed on-device).  int32 accumulate is
// exact; dequant folded into the exp2 multiplier.
// Lane 16q + 4lt + p owns gate p of unit n = 16w + 4lt + q.
// ---------------------------------------------------------------------------
__global__ __launch_bounds__(512) void lstm_kernel(
    const float* __restrict__ Whh_f, const float* __restrict__ Whh_b,
    const float* __restrict__ pre,   // [2][512 r][512 t]
    bf16_t* __restrict__ h_all)      // [512][256]  (0:125 fwd | 125:250 bwd | 250:256 zero)
{
  const int dir = blockIdx.x;
  const float* __restrict__ Whh = dir ? Whh_b : Whh_f;

  const int tid  = threadIdx.x;
  const int lane = tid & 63;
  const int w    = tid >> 6;      // wave 0..7
  const int q    = lane >> 4;     // 0..3
  const int cc   = lane & 15;
  const int lt   = cc >> 2;       // local tile 0..3
  const int p    = cc & 3;        // gate index

  // ---- pass 1: global max |Whh| over used elements ----
  float wm = 0.0f;
  #pragma unroll
  for (int LT = 0; LT < 4; ++LT) {
    int rr = 16 * (4 * w + LT) + cc;
    int nn = rr >> 2, pp = rr & 3;
    if (nn < 125) {
      const float* __restrict__ Wrow = Whh + (125 * pp + nn) * 125;
      #pragma unroll
      for (int ks = 0; ks < 2; ++ks)
        #pragma unroll
        for (int jj = 0; jj < 16; ++jj) {
          int k = 64 * ks + 16 * q + jj;
          if (k < 125) wm = fmaxf(wm, fabsf(Wrow[k]));
        }
    }
  }
  #pragma unroll
  for (int off = 1; off < 64; off <<= 1)
    wm = fmaxf(wm, __shfl_xor(wm, off));
  __shared__ float wmx[8];
  if (lane == 0) wmx[w] = wm;
  __syncthreads();
  float wmax = wmx[0];
  #pragma unroll
  for (int u = 1; u < 8; ++u) wmax = fmaxf(wmax, wmx[u]);
  const float s_w  = 127.0f / wmax;
  const float invq = wmax / (127.0f * 127.0f);   // D -> W@h

  // ---- pass 2: quantize A fragments (i8, k = 64ks + 16q + jj) ----
  int4v afrag[4][2];
  #pragma unroll
  for (int LT = 0; LT < 4; ++LT) {
    int rr = 16 * (4 * w + LT) + cc;
    int nn = rr >> 2, pp = rr & 3;
    bool avld = (nn < 125);
    const float* __restrict__ Wrow = Whh + (avld ? (125 * pp + nn) * 125 : 0);
    #pragma unroll
    for (int ks = 0; ks < 2; ++ks) {
      int4v v;
      #pragma unroll
      for (int word = 0; word < 4; ++word) {
        int b = 0;
        #pragma unroll
        for (int byte = 0; byte < 4; ++byte) {
          int jj = 4 * word + byte;
          int k  = 64 * ks + 16 * q + jj;
          int qv = 0;
          if (avld && k < 125)
            qv = (int)__builtin_rintf(Wrow[k] * s_w);
          b |= (qv & 0xFF) << (8 * byte);
        }
        v[word] = b;
      }
      afrag[LT][ks] = v;
    }
  }

  __shared__ __align__(16) char hbuf[2][128];    // int8 h, double buffered
  if (tid < 256) hbuf[tid >> 7][tid & 127] = 0;
  // zero h_all pad columns once (dir 0 only)
  if (dir == 0) {
    #pragma unroll
    for (int u = 0; u < 6; ++u) h_all[tid * 256 + 250 + u] = (bf16_t)0.0f;
  }
  __syncthreads();

  const int   r_lane = 64 * w + 16 * lt + 4 * q + p;
  const int   nset   = 16 * w + 4 * lt + q;
  const float mult   = (p == 2) ? (-2.0f * LOG2E) : (-LOG2E);
  const float sA     = (p == 2) ? 2.0f : 1.0f;
  const float sB     = (p == 2) ? -1.0f : 0.0f;
  const float dscale = mult * invq;              // int D -> exp2 argument
  const float* __restrict__ preR = pre + dir * 262144 + r_lane * 512;
  float c = 0.0f;

  float4 pv_cur = *(const float4*)preR;

  for (int g = 0; g < 128; ++g) {
    float4 pv_nxt = make_float4(0.f, 0.f, 0.f, 0.f);
    if (g < 127) pv_nxt = *(const float4*)(preR + 4 * (g + 1));

    #pragma unroll
    for (int s4 = 0; s4 < 4; ++s4) {
      const int step = 4 * g + s4;
      const int cur  = s4 & 1, nxt = cur ^ 1;
      const float pv = (s4 == 0) ? pv_cur.x : (s4 == 1) ? pv_cur.y
                     : (s4 == 2) ? pv_cur.z : pv_cur.w;
      const float pvm = mult * pv;               // off critical path

      int4v b0 = *(const int4v*)&hbuf[cur][16 * q];
      int4v b1 = *(const int4v*)&hbuf[cur][64 + 16 * q];

      int4v acc[4];
      #pragma unroll
      for (int LT = 0; LT < 4; ++LT) {
        int4v a = (int4v)0;
        a = __builtin_amdgcn_mfma_i32_16x16x64_i8(afrag[LT][0], b0, a, 0, 0, 0);
        a = __builtin_amdgcn_mfma_i32_16x16x64_i8(afrag[LT][1], b1, a, 0, 0, 0);
        acc[LT] = a;
      }

      // select D for (lt, p) from own registers
      int gl[4];
      #pragma unroll
      for (int LT = 0; LT < 4; ++LT) {
        int a01 = (p & 1) ? acc[LT][1] : acc[LT][0];
        int a23 = (p & 1) ? acc[LT][3] : acc[LT][2];
        gl[LT] = (p & 2) ? a23 : a01;
      }
      int b01 = (lt & 1) ? gl[1] : gl[0];
      int b23 = (lt & 1) ? gl[3] : gl[2];
      int gsel = (lt & 2) ? b23 : b01;

      // uniform activation: y = sigmoid(scale*(W@h + pv)); act = sA*y + sB
      float gf  = (float)gsel;
      float xg  = fmaf(gf, dscale, pvm);
      float e   = __builtin_amdgcn_exp2f(xg);
      float y   = __builtin_amdgcn_rcpf(1.0f + e);
      float act = fmaf(y, sA, sB);

      // quad: p0=i, p1=f, p2=g~, p3=o  (flat broadcast tree)
      float b_i = qperm<0x00>(act);
      float b_f = qperm<0x55>(act);
      float b_g = qperm<0xAA>(act);
      float b_o = qperm<0xFF>(act);
      c = fmaf(b_f, c, b_i * b_g);               // c = f*c + i*g~
      float e2 = __builtin_amdgcn_exp2f(-2.0f * LOG2E * c);
      float tc = fmaf(__builtin_amdgcn_rcpf(1.0f + e2), 2.0f, -1.0f);
      float h  = b_o * tc;

      if (p == 0) {
        int qh = (int)__builtin_rintf(h * 127.0f);
        hbuf[nxt][nset] = (char)qh;              // pad units stay exactly 0
        if (nset < 125) {
          int t_orig = dir ? (511 - step) : step;
          h_all[t_orig * 256 + dir * 125 + nset] = (bf16_t)h;
        }
      }
      lds_barrier();
    }
    pv_cur = pv_nxt;
  }
}

// ---------------------------------------------------------------------------
// K3: Qa[j][m] = C2 * (h @ W1[:, :250].T),  Qb[j][m] = C2 * (h @ W1[:, 250:].T + b1)
//     C2 = 2*log2(e) folded in for K4's exp2.  bf16 MFMA, one 16x16 tile/wave.
// ---------------------------------------------------------------------------
__global__ __launch_bounds__(256) void qgemm_kernel(
    const bf16_t* __restrict__ h_all, // [512][256]
    const float* __restrict__ W1,     // [512][500]
    const float* __restrict__ b1,     // [512]
    float* __restrict__ Qa,           // [512][512]
    float* __restrict__ Qb)           // [512][512]
{
  const int tid  = threadIdx.x;
  const int wv   = tid >> 6;
  const int lane = tid & 63;
  const int q    = lane >> 4, cc = lane & 15;
  const int bj   = blockIdx.x & 31;    // j tile
  const int bm   = blockIdx.x >> 5;    // m group
  const int m    = bm * 64 + wv * 16 + cc;   // [0,1024)
  const int j0   = bj * 16;
  const int jA   = j0 + cc;

  const bool isB = (m >= 512);
  const int  row = isB ? (m - 512) : m;
  const int  cof = isB ? 250 : 0;

  f32x4 acc = (f32x4)0.0f;
  #pragma unroll
  for (int ks = 0; ks < 8; ++ks) {
    int kb = 32 * ks + 8 * q;
    bf16x8 a = *(const bf16x8*)&h_all[jA * 256 + kb];
    bf16x8 b;
    #pragma unroll
    for (int jj = 0; jj < 8; ++jj) {
      int k = kb + jj;
      float v = (k < 250) ? W1[row * 500 + cof + k] : 0.0f;
      b[jj] = (bf16_t)v;
    }
    acc = __builtin_amdgcn_mfma_f32_16x16x32_bf16(a, b, acc, 0, 0, 0);
  }

  const float C2 = 2.0f * LOG2E;
  #pragma unroll
  for (int reg = 0; reg < 4; ++reg) {
    int j = j0 + 4 * q + reg;
    float v = acc[reg];
    if (!isB) Qa[j * 512 + m] = C2 * v;
    else      Qb[j * 512 + (m - 512)] = C2 * (v + b1[m - 512]);
  }
}

// ---------------------------------------------------------------------------
// K4: out[i][j] = b2 + sum_k W2[k] * tanh(...)
//     tanh = 1 - 2*rcp(1 + exp2(sa[j,k] + sb[i,k]))   (C2 pre-folded)
//     accumulate accR = sum w*r;  out = wsum - 2*accR + b2
// ---------------------------------------------------------------------------
__global__ __launch_bounds__(256) void outer_kernel(
    const float* __restrict__ Qa, const float* __restrict__ Qb,
    const float* __restrict__ W2, const float* __restrict__ b2,
    float* __restrict__ out)
{
  __shared__ float sa[2][32][33];
  __shared__ float sb[2][32][33];
  __shared__ float sw[2][32];

  const int tid = threadIdx.x;
  const int bi  = blockIdx.x >> 4, bjx = blockIdx.x & 15;
  const int i0  = bi * 32, j0 = bjx * 32;
  const int ii0 = (tid & 15) * 2;
  const int jj0 = (tid >> 4) * 2;
  const int ljj = tid & 31, kk4 = (tid >> 5) * 4;

  float accR[2][2] = {{0.0f, 0.0f}, {0.0f, 0.0f}};
  float wsum = 0.0f;

  for (int kc = 0; kc < 16; ++kc) {
    const int buf = kc & 1;
    const int k0  = kc * 32;
    float4 va = *(const float4*)&Qa[(j0 + ljj) * 512 + k0 + kk4];
    float4 vb = *(const float4*)&Qb[(i0 + ljj) * 512 + k0 + kk4];
    sa[buf][kk4 + 0][ljj] = va.x; sa[buf][kk4 + 1][ljj] = va.y;
    sa[buf][kk4 + 2][ljj] = va.z; sa[buf][kk4 + 3][ljj] = va.w;
    sb[buf][kk4 + 0][ljj] = vb.x; sb[buf][kk4 + 1][ljj] = vb.y;
    sb[buf][kk4 + 2][ljj] = vb.z; sb[buf][kk4 + 3][ljj] = vb.w;
    if (tid < 32) sw[buf][tid] = W2[k0 + tid];
    __syncthreads();

    #pragma unroll 4
    for (int kk = 0; kk < 32; ++kk) {
      float2 av = *(const float2*)&sa[buf][kk][jj0];
      float2 bv = *(const float2*)&sb[buf][kk][ii0];
      float wk = sw[buf][kk];
      wsum += wk;
      {
        float e = __builtin_amdgcn_exp2f(av.x + bv.x);
        accR[0][0] = fmaf(wk, __builtin_amdgcn_rcpf(1.0f + e), accR[0][0]);
      }
      {
        float e = __builtin_amdgcn_exp2f(av.y + bv.x);
        accR[0][1] = fmaf(wk, __builtin_amdgcn_rcpf(1.0f + e), accR[0][1]);
      }
      {
        float e = __builtin_amdgcn_exp2f(av.x + bv.y);
        accR[1][0] = fmaf(wk, __builtin_amdgcn_rcpf(1.0f + e), accR[1][0]);
      }
      {
        float e = __builtin_amdgcn_exp2f(av.y + bv.y);
        accR[1][1] = fmaf(wk, __builtin_amdgcn_rcpf(1.0f + e), accR[1][1]);
      }
    }
  }

  const float bb = b2[0];
  #pragma unroll
  for (int i2 = 0; i2 < 2; ++i2)
    #pragma unroll
    for (int j2 = 0; j2 < 2; ++j2)
      out[(i0 + ii0 + i2) * 512 + (j0 + jj0 + j2)] =
          wsum - 2.0f * accR[i2][j2] + bb;
}

// ---------------------------------------------------------------------------
extern "C" void kernel_launch(void* const* d_in, const int* in_sizes, int n_in,
                              void* d_out, int out_size, void* d_ws, size_t ws_size,
                              hipStream_t stream) {
  const float* emb   = (const float*)d_in[0];
  const float* Wih_f = (const float*)d_in[1];
  const float* Whh_f = (const float*)d_in[2];
  const float* bih_f = (const float*)d_in[3];
  const float* bhh_f = (const float*)d_in[4];
  const float* Wih_b = (const float*)d_in[5];
  const float* Whh_b = (const float*)d_in[6];
  const float* bih_b = (const float*)d_in[7];
  const float* bhh_b = (const float*)d_in[8];
  const float* W1    = (const float*)d_in[9];
  const float* b1    = (const float*)d_in[10];
  const float* W2    = (const float*)d_in[11];
  const float* b2    = (const float*)d_in[12];
  float* out = (float*)d_out;

  char* ws = (char*)d_ws;
  float*  pre   = (float*)ws;                                  // 2 MB
  bf16_t* h_all = (bf16_t*)(ws + 2 * 1024 * 1024);             // 256 KB
  float*  Qa    = (float*)(ws + 2 * 1024 * 1024 + 256 * 1024); // 1 MB
  float*  Qb    = Qa + 512 * 512;                              // 1 MB

  pre_kernel<<<64, 256, 0, stream>>>(emb, Wih_f, bih_f, bhh_f,
                                     Wih_b, bih_b, bhh_b, pre);
  lstm_kernel<<<2, 512, 0, stream>>>(Whh_f, Whh_b, pre, h_all);
  qgemm_kernel<<<512, 256, 0, stream>>>(h_all, W1, b1, Qa, Qb);
  outer_kernel<<<256, 256, 0, stream>>>(Qa, Qb, W2, b2, out);
}